// Round 18
// baseline (38.635 us; speedup 1.0000x reference)
//
#include <hip/hip_runtime.h>

// MPS batched contraction via SITE PAIRING (R9/R11/R13-verified):
// G_P[l][pq][d] = Σ_m A_{2P}[l,p,m] A_{2P+1}[m,q,d],  xx[pq] = x_p * y_q,
// left'' = G_P(xx) left.  32 pairs, K=128 each, 32x32x16 f16 MFMA:
//   A-op (G): row d = lane&31, k = 8*(lane>>5) + e
//   B-op (U): col b = lane&31, same k;  C/D: col = lane&31,
//   row l = (reg&3) + 8*(reg>>2) + 4*(lane>>5)
// G-frag kf = pq*2+lh encodes l = 16*lh + (e&3) + 8*(e>>2) + 4*h =>
//   U_frag(kf) = f16(left[e + 8*lh]) * xx[pq]  -- SAME LANE.
//
// R18 = R13 minus the entire G-LDS + barrier machinery. R1-R17 falsified
// LDS BW, chain depth, G pipe choice, x path, prep, TLP, vmcnt drain; the
// remaining structural constant was one s_barrier per chunk, which phase-
// convoys all 8 waves/CU: simultaneous ds_read bursts (64 x b128 ~ 770cy
// serialized LDS time) alternating with simultaneous MFMA bursts -- pipes
// see sum-of-phases, not max. G (256KB, L2/L3-resident) is now read JIT
// from GLOBAL per pair (8 x dwordx4, 16B/lane coalesced, L1-shared across
// the CU's waves); NO barriers after the x prologue -- waves free-run.
// Numerics identical to R13 -> absmax 0.0078125.

typedef _Float16 half8 __attribute__((ext_vector_type(8)));
typedef _Float16 half4 __attribute__((ext_vector_type(4)));
typedef float floatx16 __attribute__((ext_vector_type(16)));
typedef float f32x4 __attribute__((ext_vector_type(4)));

#define NPAIRS 32
#define XSTRIDE 129     // padded half4 units per quad line (bank spread)

// ---------------- prep: one block per (pair, pq) (R16-proven) -------------
__global__ void mps_prep_pair(const float* __restrict__ A, _Float16* __restrict__ Gf) {
    __shared__ float sA[1024];   // [l][m]
    __shared__ float sB[1024];   // [m][d]
    __shared__ float sG[1024];   // [l][d]
    const int blk = blockIdx.x;          // 0..127 = P*4 + pq
    const int P   = blk >> 2;
    const int pq  = blk & 3;
    const int p   = pq >> 1, q = pq & 1;
    const int tid = threadIdx.x;         // 0..255
    const int row = tid >> 3;            // 0..31
    const int c4  = (tid & 7) * 4;       // 0,4,...,28

    *(f32x4*)&sA[row * 32 + c4] =
        *(const f32x4*)(A + ((size_t)(2 * P) * 32 + row) * 64 + p * 32 + c4);
    *(f32x4*)&sB[row * 32 + c4] =
        *(const f32x4*)(A + ((size_t)(2 * P + 1) * 32 + row) * 64 + q * 32 + c4);
    __syncthreads();
    {
        f32x4 acc;
        acc[0] = 0.f; acc[1] = 0.f; acc[2] = 0.f; acc[3] = 0.f;
        for (int m = 0; m < 32; ++m) {
            const float av = sA[row * 32 + m];
            const f32x4 bv = *(const f32x4*)&sB[m * 32 + c4];
            acc[0] += av * bv[0]; acc[1] += av * bv[1];
            acc[2] += av * bv[2]; acc[3] += av * bv[3];
        }
        *(f32x4*)&sG[row * 32 + c4] = acc;
    }
    __syncthreads();
    if (tid < 128) {
        const int lh   = tid >> 6;
        const int lane = tid & 63;
        const int h    = lane >> 5;
        const int d    = lane & 31;
        half8 v;
#pragma unroll
        for (int e = 0; e < 8; ++e) {
            const int l = 16 * lh + (e & 3) + 8 * (e >> 2) + 4 * h;
            v[e] = (_Float16)sG[l * 32 + d];
        }
        reinterpret_cast<half8*>(Gf)[((size_t)P * 8 + pq * 2 + lh) * 64 + lane] = v;
    }
}

// ---------------- main kernel ----------------
#define MF32(A_, B_, C_) __builtin_amdgcn_mfma_f32_32x32x16_f16(A_, B_, C_, 0, 0, 0)

// One pair: x quad from LDS (b64, lanes 32-63 broadcast), 8 JIT G reads
// FROM GLOBAL (L1/L2-hot, coalesced), FA cvt from acc, 8-MFMA in-place chain.
#define PAIRDO(P)                                                             \
    {                                                                         \
        const half4 xq_ = smX[(P) * XSTRIDE + r];                             \
        const _Float16 w00_ = xq_[0] * xq_[2];                                \
        const _Float16 w01_ = xq_[0] * xq_[3];                                \
        const _Float16 w10_ = xq_[1] * xq_[2];                                \
        const _Float16 w11_ = xq_[1] * xq_[3];                                \
        half8 G_[8];                                                          \
        _Pragma("unroll")                                                     \
        for (int f_ = 0; f_ < 8; ++f_)                                        \
            G_[f_] = gfp[((P) * 8 + f_) * 64 + lane];                         \
        half8 FA0_, FA1_;                                                     \
        _Pragma("unroll")                                                     \
        for (int i_ = 0; i_ < 8; ++i_) {                                      \
            FA0_[i_] = (_Float16)acc[i_];                                     \
            FA1_[i_] = (_Float16)acc[8 + i_];                                 \
        }                                                                     \
        floatx16 t_;                                                          \
        t_ = MF32(G_[0], FA0_ * w00_, zv);                                    \
        t_ = MF32(G_[1], FA1_ * w00_, t_);                                    \
        t_ = MF32(G_[2], FA0_ * w01_, t_);                                    \
        t_ = MF32(G_[3], FA1_ * w01_, t_);                                    \
        t_ = MF32(G_[4], FA0_ * w10_, t_);                                    \
        t_ = MF32(G_[5], FA1_ * w10_, t_);                                    \
        t_ = MF32(G_[6], FA0_ * w11_, t_);                                    \
        t_ = MF32(G_[7], FA1_ * w11_, t_);                                    \
        acc = t_;                                                             \
    }

__global__ __launch_bounds__(256, 2) void mps_main(const float* __restrict__ x,
                                                   const _Float16* __restrict__ Gf,
                                                   float* __restrict__ out) {
    __shared__ __align__(8) half4 smX[32 * XSTRIDE];  // 33 KB, [quad][row]

    const int tid  = threadIdx.x;
    const int lane = tid & 63;
    const int wid  = tid >> 6;                 // 0..3
    const int brow = blockIdx.x * 128;         // block's first batch row
    const int col  = lane & 31;
    const int r    = wid * 32 + col;           // this wave's row within block

    const half8* gfp = reinterpret_cast<const half8*>(Gf);

    // x -> LDS f16 transposed [quad][row]: coalesced f32x4 global reads
    // (flat quad index j: lane-consecutive addresses), free-2-way ds_writes.
#pragma unroll
    for (int i = 0; i < 16; ++i) {
        const int j   = i * 256 + tid;         // 0..4095
        const int row = j >> 5, q = j & 31;
        const f32x4 v = *(const f32x4*)(x + (size_t)(brow + row) * 128 + 4 * q);
        half4 hv;
        hv[0] = (_Float16)v[0]; hv[1] = (_Float16)v[1];
        hv[2] = (_Float16)v[2]; hv[3] = (_Float16)v[3];
        smX[q * XSTRIDE + row] = hv;
    }

    floatx16 zv;
#pragma unroll
    for (int i = 0; i < 16; ++i) zv[i] = 0.f;

    // acc = left[l], l = (reg&3) + 8*(reg>>2) + 4*(lane>>5)
    floatx16 acc;
#pragma unroll
    for (int i = 0; i < 16; ++i) acc[i] = 0.f;
    if (lane < 32) acc[0] = 1.f;               // left0 = e0

    __syncthreads();                            // x ready -- the ONLY barrier

    // 32 pairs, no barriers: waves free-run; G reads hit L1/L2.
#pragma unroll
    for (int P = 0; P < 32; ++P) {
        PAIRDO(P)
    }

    // out[b] = left_final[l=0]: reg 0, h=0 -> lanes 0..31
    if (lane < 32) out[brow + wid * 32 + lane] = acc[0];
}

extern "C" void kernel_launch(void* const* d_in, const int* in_sizes, int n_in,
                              void* d_out, int out_size, void* d_ws, size_t ws_size,
                              hipStream_t stream) {
    const float* x = (const float*)d_in[0];   // [65536][64][2] f32
    const float* A = (const float*)d_in[1];   // [64][32][2][32] f32
    float* outp = (float*)d_out;              // [65536] f32
    _Float16* Gf = (_Float16*)d_ws;           // 256 KB pair-fragment fp16

    hipLaunchKernelGGL(mps_prep_pair, dim3(NPAIRS * 4), dim3(256), 0, stream, A, Gf);
    hipLaunchKernelGGL(mps_main, dim3(65536 / 128), dim3(256), 0, stream, x, Gf, outp);
}

// Round 19
// 29.860 us; speedup vs baseline: 1.2939x; 1.2939x over previous
//
#include <hip/hip_runtime.h>

// MPS batched contraction via SITE PAIRING (R9/R11/R13-verified):
// G_P[l][pq][d] = Σ_m A_{2P}[l,p,m] A_{2P+1}[m,q,d],  xx[pq] = x_p * y_q,
// left'' = G_P(xx) left.  32 pairs, K=128 each, 32x32x16 f16 MFMA:
//   A-op (G): row d = lane&31, k = 8*(lane>>5) + e
//   B-op (U): col b = lane&31, same k;  C/D: col = lane&31,
//   row l = (reg&3) + 8*(reg>>2) + 4*(lane>>5)
// G-frag kf = pq*2+lh encodes l = 16*lh + (e&3) + 8*(e>>2) + 4*h =>
//   U_frag(kf) = f16(left[e + 8*lh]) * xx[pq]  -- SAME LANE.
//
// R19 = R16 with ONE change: the main loop is ROLLED (#pragma unroll 1).
// Every variant R1-R18 fully unrolled 16-32 chunk bodies (~15-30 KB of
// straight-line code) -- streams the 32KB icache with zero reuse, a stall
// invisible to MfmaUtil/VALUBusy and invariant to occupancy/LDS/barriers,
// matching the unexplained ~2000cy/pair. Rolled body ~140 insts (~1.2KB).
// Runtime indices go only into LDS/global ADDRESSES (register arrays stay
// statically indexed -- no scratch). Everything else byte-identical to R16.

typedef _Float16 half8 __attribute__((ext_vector_type(8)));
typedef _Float16 half4 __attribute__((ext_vector_type(4)));
typedef float floatx16 __attribute__((ext_vector_type(16)));
typedef float f32x4 __attribute__((ext_vector_type(4)));

#define NPAIRS 32
#define GCH 8192        // halfs per 2-pair G chunk = 16 KB
#define XSTRIDE 129     // padded half4 units per quad line (bank spread)

// ---------------- prep: one block per (pair, pq) (R16-proven) -------------
__global__ void mps_prep_pair(const float* __restrict__ A, _Float16* __restrict__ Gf) {
    __shared__ float sA[1024];   // [l][m]
    __shared__ float sB[1024];   // [m][d]
    __shared__ float sG[1024];   // [l][d]
    const int blk = blockIdx.x;          // 0..127 = P*4 + pq
    const int P   = blk >> 2;
    const int pq  = blk & 3;
    const int p   = pq >> 1, q = pq & 1;
    const int tid = threadIdx.x;         // 0..255
    const int row = tid >> 3;            // 0..31
    const int c4  = (tid & 7) * 4;       // 0,4,...,28

    *(f32x4*)&sA[row * 32 + c4] =
        *(const f32x4*)(A + ((size_t)(2 * P) * 32 + row) * 64 + p * 32 + c4);
    *(f32x4*)&sB[row * 32 + c4] =
        *(const f32x4*)(A + ((size_t)(2 * P + 1) * 32 + row) * 64 + q * 32 + c4);
    __syncthreads();
    {
        f32x4 acc;
        acc[0] = 0.f; acc[1] = 0.f; acc[2] = 0.f; acc[3] = 0.f;
        for (int m = 0; m < 32; ++m) {
            const float av = sA[row * 32 + m];
            const f32x4 bv = *(const f32x4*)&sB[m * 32 + c4];
            acc[0] += av * bv[0]; acc[1] += av * bv[1];
            acc[2] += av * bv[2]; acc[3] += av * bv[3];
        }
        *(f32x4*)&sG[row * 32 + c4] = acc;
    }
    __syncthreads();
    if (tid < 128) {
        const int lh   = tid >> 6;
        const int lane = tid & 63;
        const int h    = lane >> 5;
        const int d    = lane & 31;
        half8 v;
#pragma unroll
        for (int e = 0; e < 8; ++e) {
            const int l = 16 * lh + (e & 3) + 8 * (e >> 2) + 4 * h;
            v[e] = (_Float16)sG[l * 32 + d];
        }
        reinterpret_cast<half8*>(Gf)[((size_t)P * 8 + pq * 2 + lh) * 64 + lane] = v;
    }
}

// ---------------- main kernel ----------------
#define MF32(A_, B_, C_) __builtin_amdgcn_mfma_f32_32x32x16_f16(A_, B_, C_, 0, 0, 0)

__global__ __launch_bounds__(256, 2) void mps_main(const float* __restrict__ x,
                                                   const _Float16* __restrict__ Gf,
                                                   float* __restrict__ out) {
    __shared__ __align__(16) _Float16 smG[2 * GCH];       // 32 KB
    __shared__ __align__(8)  half4    smX[32 * XSTRIDE];  // 33 KB, [quad][row]

    const int tid  = threadIdx.x;
    const int lane = tid & 63;
    const int wid  = tid >> 6;                 // 0..3
    const int brow = blockIdx.x * 128;         // block's first batch row
    const int col  = lane & 31;
    const int r    = wid * 32 + col;           // this wave's row within block

    // stage chunk 0 (runtime-style helper used below too)
#pragma unroll
    for (int r_ = 0; r_ < 4; ++r_) {
        const int rec = r_ * 4 + wid;
        const _Float16* g = Gf + rec * 512 + lane * 8;
        __builtin_amdgcn_global_load_lds(
            (const __attribute__((address_space(1))) void*)g,
            (__attribute__((address_space(3))) void*)&smG[rec * 512],
            16, 0, 0);
    }

    // x -> LDS f16 transposed [quad][row]: coalesced f32x4 global reads
#pragma unroll
    for (int i = 0; i < 16; ++i) {
        const int j   = i * 256 + tid;         // 0..4095
        const int row = j >> 5, q = j & 31;
        const f32x4 v = *(const f32x4*)(x + (size_t)(brow + row) * 128 + 4 * q);
        half4 hv;
        hv[0] = (_Float16)v[0]; hv[1] = (_Float16)v[1];
        hv[2] = (_Float16)v[2]; hv[3] = (_Float16)v[3];
        smX[q * XSTRIDE + row] = hv;
    }

    floatx16 zv;
#pragma unroll
    for (int i = 0; i < 16; ++i) zv[i] = 0.f;

    // acc = left[l], l = (reg&3) + 8*(reg>>2) + 4*(lane>>5)
    floatx16 acc;
#pragma unroll
    for (int i = 0; i < 16; ++i) acc[i] = 0.f;
    if (lane < 32) acc[0] = 1.f;               // left0 = e0

    __syncthreads();                            // x in LDS + G chunk 0 ready

    // ROLLED main loop: 16 chunks x 2 pairs. Body ~1.2KB -> icache-resident.
#pragma unroll 1
    for (int C = 0; C < 16; ++C) {
        const int buf = C & 1;
        if (C < 15) {
            const int nbuf = buf ^ 1;
#pragma unroll
            for (int r_ = 0; r_ < 4; ++r_) {
                const int rec = r_ * 4 + wid;
                const _Float16* g = Gf + (size_t)(C + 1) * GCH + rec * 512 + lane * 8;
                __builtin_amdgcn_global_load_lds(
                    (const __attribute__((address_space(1))) void*)g,
                    (__attribute__((address_space(3))) void*)&smG[nbuf * GCH + rec * 512],
                    16, 0, 0);
            }
        }
#pragma unroll
        for (int LP = 0; LP < 2; ++LP) {
            const int P = 2 * C + LP;
            const half4 xq = smX[P * XSTRIDE + r];
            const _Float16 w00 = xq[0] * xq[2];
            const _Float16 w01 = xq[0] * xq[3];
            const _Float16 w10 = xq[1] * xq[2];
            const _Float16 w11 = xq[1] * xq[3];
            half8 G0, G1, G2, G3, G4, G5, G6, G7;
            {
                const _Float16* gb = &smG[buf * GCH + LP * 8 * 512 + lane * 8];
                G0 = *(const half8*)(gb + 0 * 512);
                G1 = *(const half8*)(gb + 1 * 512);
                G2 = *(const half8*)(gb + 2 * 512);
                G3 = *(const half8*)(gb + 3 * 512);
                G4 = *(const half8*)(gb + 4 * 512);
                G5 = *(const half8*)(gb + 5 * 512);
                G6 = *(const half8*)(gb + 6 * 512);
                G7 = *(const half8*)(gb + 7 * 512);
            }
            half8 FA0, FA1;
#pragma unroll
            for (int i_ = 0; i_ < 8; ++i_) {
                FA0[i_] = (_Float16)acc[i_];
                FA1[i_] = (_Float16)acc[8 + i_];
            }
            floatx16 t;
            t = MF32(G0, FA0 * w00, zv);
            t = MF32(G1, FA1 * w00, t);
            t = MF32(G2, FA0 * w01, t);
            t = MF32(G3, FA1 * w01, t);
            t = MF32(G4, FA0 * w10, t);
            t = MF32(G5, FA1 * w10, t);
            t = MF32(G6, FA0 * w11, t);
            t = MF32(G7, FA1 * w11, t);
            acc = t;
        }
        __syncthreads();
    }

    // out[b] = left_final[l=0]: reg 0, h=0 -> lanes 0..31
    if (lane < 32) out[brow + wid * 32 + lane] = acc[0];
}

extern "C" void kernel_launch(void* const* d_in, const int* in_sizes, int n_in,
                              void* d_out, int out_size, void* d_ws, size_t ws_size,
                              hipStream_t stream) {
    const float* x = (const float*)d_in[0];   // [65536][64][2] f32
    const float* A = (const float*)d_in[1];   // [64][32][2][32] f32
    float* outp = (float*)d_out;              // [65536] f32
    _Float16* Gf = (_Float16*)d_ws;           // 256 KB pair-fragment fp16

    hipLaunchKernelGGL(mps_prep_pair, dim3(NPAIRS * 4), dim3(256), 0, stream, A, Gf);
    hipLaunchKernelGGL(mps_main, dim3(65536 / 128), dim3(256), 0, stream, x, Gf, outp);
}